// Round 3
// baseline (148.923 us; speedup 1.0000x reference)
//
#include <hip/hip_runtime.h>
#include <hip/hip_bf16.h>

#define NPIX 4096
#define CIN  256
#define DK   32

typedef __attribute__((ext_vector_type(8))) short short8;     // 8 bf16 = one MFMA A/B frag reg group
typedef __attribute__((ext_vector_type(16))) float f32x16;    // 32x32 C/D frag

__device__ __forceinline__ unsigned short f2bf(float f) {
    unsigned int u = __float_as_uint(f);
    return (unsigned short)((u + 0x7fffu + ((u >> 16) & 1u)) >> 16);   // RNE
}
__device__ __forceinline__ float bf2f(unsigned short h) {
    return __uint_as_float(((unsigned int)h) << 16);
}
// packed fp32x2 -> bf16x2 via v_cvt_pk_bf16_f32 (RNE), low short = a
__device__ __forceinline__ unsigned int f2bf2(float a, float b) {
    __hip_bfloat162 h = __float22bfloat162_rn(make_float2(a, b));
    unsigned int u;
    __builtin_memcpy(&u, &h, 4);
    return u;
}

// ---------------------------------------------------------------------------
// Weight prep: wq/wk hi+residual B-frags, wv hi B-frags.
// grid (16 kchunks, 12), 64 threads.
__global__ void wprep_kernel(const float* __restrict__ wq, const float* __restrict__ wk,
                             const float* __restrict__ wv,
                             unsigned short* __restrict__ wqh, unsigned short* __restrict__ wql,
                             unsigned short* __restrict__ wkh, unsigned short* __restrict__ wkl,
                             unsigned short* __restrict__ wvh) {
    const int lane = threadIdx.x & 63, li = lane & 31, hi = lane >> 5;
    const int kc = blockIdx.x, y = blockIdx.y;
    if (y < 4) {
        const float* m = (y < 2) ? wq : wk;
        short8 h8, l8;
#pragma unroll
        for (int e = 0; e < 8; ++e) {
            float v = m[li * CIN + kc * 16 + hi * 8 + e];
            unsigned short hb = f2bf(v);
            h8[e] = (short)hb;
            l8[e] = (short)f2bf(v - bf2f(hb));
        }
        unsigned short* dst = (y == 0) ? wqh : (y == 1) ? wql : (y == 2) ? wkh : wkl;
        *reinterpret_cast<short8*>(&dst[kc * 512 + lane * 8]) = (y & 1) ? l8 : h8;
    } else {
        const int cblk = y - 4;
        short8 h8;
#pragma unroll
        for (int e = 0; e < 8; ++e)
            h8[e] = (short)f2bf(wv[(cblk * 32 + li) * CIN + kc * 16 + hi * 8 + e]);
        *reinterpret_cast<short8*>(&wvh[(cblk * 16 + kc) * 512 + lane * 8]) = h8;
    }
}

// ---------------------------------------------------------------------------
// Fused prep + Q/K/V projection (unchanged). grid (128, 4), block 512.
__global__ __launch_bounds__(512) void projall_kernel(
        const float* __restrict__ x,
        const unsigned short* __restrict__ wqh, const unsigned short* __restrict__ wql,
        const unsigned short* __restrict__ wkh, const unsigned short* __restrict__ wkl,
        const unsigned short* __restrict__ wvh,
        const float* __restrict__ bq, const float* __restrict__ bk, const float* __restrict__ bv,
        unsigned short* __restrict__ qfrag, unsigned short* __restrict__ kfrag,
        unsigned short* __restrict__ vfrag) {
    __shared__ float xs[64][36];
    __shared__ unsigned short xhf[16 * 512];
    __shared__ unsigned short xlf[16 * 512];
    __shared__ unsigned short ts[2][32][40];

    const int t = threadIdx.x, lane = t & 63, li = lane & 31, hi = lane >> 5, w = t >> 6;
    const int nblk = blockIdx.x, b = blockIdx.y;
    const int n0 = nblk * 32;

    for (int cb = 0; cb < 4; ++cb) {
        {
            int c = t >> 3, n4 = (t & 7) * 4;
            float4 v = *reinterpret_cast<const float4*>(
                &x[(size_t)(b * CIN + cb * 64 + c) * NPIX + n0 + n4]);
            xs[c][n4 + 0] = v.x; xs[c][n4 + 1] = v.y;
            xs[c][n4 + 2] = v.z; xs[c][n4 + 3] = v.w;
        }
        __syncthreads();
        {
            const int kc = w & 3;
            const bool isL = (w >= 4);
            short8 f;
#pragma unroll
            for (int e = 0; e < 8; ++e) {
                float v = xs[kc * 16 + hi * 8 + e][li];
                unsigned short hb = f2bf(v);
                f[e] = isL ? (short)f2bf(v - bf2f(hb)) : (short)hb;
            }
            unsigned short* dst = isL ? xlf : xhf;
            *reinterpret_cast<short8*>(&dst[(cb * 4 + kc) * 512 + lane * 8]) = f;
        }
        __syncthreads();
    }

    if (w < 2) {
        const unsigned short* wh = (w == 0) ? wqh : wkh;
        const unsigned short* wl = (w == 0) ? wql : wkl;
        const float* bias = (w == 0) ? bq : bk;
        f32x16 acc;
#pragma unroll
        for (int r = 0; r < 16; ++r) acc[r] = 0.f;
        for (int kc = 0; kc < 16; ++kc) {
            short8 ah = *reinterpret_cast<const short8*>(&xhf[kc * 512 + lane * 8]);
            short8 al = *reinterpret_cast<const short8*>(&xlf[kc * 512 + lane * 8]);
            short8 whf = *reinterpret_cast<const short8*>(&wh[kc * 512 + lane * 8]);
            short8 wlf = *reinterpret_cast<const short8*>(&wl[kc * 512 + lane * 8]);
            acc = __builtin_amdgcn_mfma_f32_32x32x16_bf16(ah, whf, acc, 0, 0, 0);
            acc = __builtin_amdgcn_mfma_f32_32x32x16_bf16(al, whf, acc, 0, 0, 0);
            acc = __builtin_amdgcn_mfma_f32_32x32x16_bf16(ah, wlf, acc, 0, 0, 0);
        }
        const float bs = bias[li];
#pragma unroll
        for (int r = 0; r < 16; ++r) {
            int row = (r & 3) + 8 * (r >> 2) + 4 * hi;
            ts[w][row][li] = f2bf(acc[r] + bs);
        }
        unsigned short* dstf = (w == 0) ? qfrag : kfrag;
#pragma unroll
        for (int dh = 0; dh < 2; ++dh) {
            short8 f = *reinterpret_cast<const short8*>(&ts[w][li][dh * 16 + hi * 8]);
            *reinterpret_cast<short8*>(
                &dstf[((size_t)(b * 128 + nblk) * 2 + dh) * 512 + lane * 8]) = f;
        }
    } else {
        const int w2 = w - 2;
        const int njob = (w2 < 2) ? 2 : 1;
        for (int jj = 0; jj < njob; ++jj) {
            const int cblk = w2 + jj * 6;
            f32x16 acc;
#pragma unroll
            for (int r = 0; r < 16; ++r) acc[r] = 0.f;
            for (int kc = 0; kc < 16; ++kc) {
                short8 xb = *reinterpret_cast<const short8*>(&xhf[kc * 512 + lane * 8]);
                short8 wf = *reinterpret_cast<const short8*>(&wvh[(cblk * 16 + kc) * 512 + lane * 8]);
                acc = __builtin_amdgcn_mfma_f32_32x32x16_bf16(xb, wf, acc, 0, 0, 0);
            }
            const float bvv = bv[cblk * 32 + li];
#pragma unroll
            for (int g = 0; g < 2; ++g) {
                short8 sv;
#pragma unroll
                for (int e = 0; e < 8; ++e) sv[e] = (short)f2bf(acc[g * 8 + e] + bvv);
                *reinterpret_cast<short8*>(
                    &vfrag[((size_t)(b * 8 + cblk) * 256 + nblk * 2 + g) * 512 + lane * 8]) = sv;
            }
        }
    }
}

// ---------------------------------------------------------------------------
// Fused attention, j-split, SPECIALIZED waves (de-convoy): block = 512 threads
// (8 waves). Waves 0-3 are E-waves: wave sl computes QK^T+exp for BOTH i-tiles
// (it=0,1) of its 32-j slice (K frags shared across it -> K traffic halved).
// Waves 4-7 are PV-waves: wave w owns TWO cq units (cqa=w-4, cqb=w), 32 MFMA
// per step, single rolling vp[8] register V buffer (phase A consumes cqa and
// prefetches cqb of the same step; phase B consumes cqb and prefetches cqa of
// the next step -> every load has >=450 cyc of MFMA cover).
//
// Waves round-robin to SIMDs, so each SIMD hosts 2 E + 2 PV waves (2 blk/CU):
// E-waves' exp/pack VALU runs CONCURRENTLY with PV-waves' MFMA stream. The
// previous symmetric design phase-locked all waves (E->exp->PV in lockstep via
// the per-step barrier), so matrix and VALU pipes alternated instead of
// overlapping: step = sum(2300 matrix + 2100 VALU + 2700 L2) = 7200 cyc.
// With role-split the step floor is max(...) ~ 2700-3500 cyc.
__global__ __launch_bounds__(512, 4) void attnv_kernel(
        const unsigned short* __restrict__ qfrag, const unsigned short* __restrict__ kfrag,
        const unsigned short* __restrict__ vfrag, unsigned short* __restrict__ opart,
        float* __restrict__ lpart, float* __restrict__ out) {
    __shared__ unsigned short Ps[4 * 8 * 512];   // [it*2+buf][jg 8][lane*8], 32 KB
    __shared__ float sred[2][4][32];

    const int t = threadIdx.x, lane = t & 63, li = lane & 31, hi = lane >> 5, w = t >> 6;
    const int blk = blockIdx.x;
    const int xcd = blk & 7, slot = blk >> 3;
    const int jh = slot & 1, ps = slot >> 1;
    const int b = xcd >> 1;
    const int ipos = (xcd & 1) * 32 + ps;          // 64-i tile in [0,64)

    if (w < 4) {
        // ------------------------- E-waves: sl = w, both it ------------------
        const int sl = w;
        short8 qb00, qb01, qb10, qb11;
        {
            size_t q0 = ((size_t)(b * 128 + ipos * 2 + 0) * 2) * 512 + lane * 8;
            size_t q1 = ((size_t)(b * 128 + ipos * 2 + 1) * 2) * 512 + lane * 8;
            qb00 = *reinterpret_cast<const short8*>(&qfrag[q0]);
            qb01 = *reinterpret_cast<const short8*>(&qfrag[q0 + 512]);
            qb10 = *reinterpret_cast<const short8*>(&qfrag[q1]);
            qb11 = *reinterpret_cast<const short8*>(&qfrag[q1 + 512]);
        }
        float ssum0 = 0.f, ssum1 = 0.f;
        short8 kp0, kp1;                           // K frags for step s (shared by both it)

        auto kload = [&](int s) {
            size_t koff = ((size_t)(b * 128 + jh * 64 + s * 4 + sl) * 2) * 512 + lane * 8;
            kp0 = *reinterpret_cast<const short8*>(&kfrag[koff]);
            kp1 = *reinterpret_cast<const short8*>(&kfrag[koff + 512]);
        };
        auto eunit = [&](short8 qA, short8 qB, float& ss, int slab, int buf) {
            f32x16 e;
#pragma unroll
            for (int r = 0; r < 16; ++r) e[r] = 0.f;
            e = __builtin_amdgcn_mfma_f32_32x32x16_bf16(kp0, qA, e, 0, 0, 0);
            e = __builtin_amdgcn_mfma_f32_32x32x16_bf16(kp1, qB, e, 0, 0, 0);
#pragma unroll
            for (int g = 0; g < 2; ++g) {
                float p0 = __expf(e[g * 8 + 0]), p1 = __expf(e[g * 8 + 1]);
                float p2 = __expf(e[g * 8 + 2]), p3 = __expf(e[g * 8 + 3]);
                float p4 = __expf(e[g * 8 + 4]), p5 = __expf(e[g * 8 + 5]);
                float p6 = __expf(e[g * 8 + 6]), p7 = __expf(e[g * 8 + 7]);
                ss += ((p0 + p1) + (p2 + p3)) + ((p4 + p5) + (p6 + p7));
                uint4 pk;
                pk.x = f2bf2(p0, p1); pk.y = f2bf2(p2, p3);
                pk.z = f2bf2(p4, p5); pk.w = f2bf2(p6, p7);
                *reinterpret_cast<uint4*>(
                    &Ps[((slab + buf) * 8 + sl * 2 + g) * 512 + lane * 8]) = pk;
            }
        };
        auto do_E2 = [&](int s) {
            const int buf = s & 1;
            eunit(qb00, qb01, ssum0, 0, buf);      // it = 0 -> slabs 0/1
            eunit(qb10, qb11, ssum1, 2, buf);      // it = 1 -> slabs 2/3
        };

        kload(0);
        do_E2(0);
        kload(1);
        __syncthreads();                           // (1)
#pragma unroll 1
        for (int s = 0; s < 16; ++s) {
            if (s + 1 < 16) {
                do_E2(s + 1);                      // writes buf (s+1)&1
                if (s + 2 < 16) kload(s + 2);
            }
            __syncthreads();                       // (2..17)
        }

        // row sums
        ssum0 += __shfl_xor(ssum0, 32);
        ssum1 += __shfl_xor(ssum1, 32);
        if (lane < 32) { sred[0][sl][li] = ssum0; sred[1][sl][li] = ssum1; }
        __syncthreads();                           // (18)
        if (w < 2 && lane < 32) {
            float lt = sred[w][0][li] + sred[w][1][li] + sred[w][2][li] + sred[w][3][li];
            lpart[((size_t)jh * 4 + b) * NPIX + ipos * 64 + w * 32 + li] = lt;
        }
    } else {
        // ---------------- PV-waves: cqa = w-4 (c 0..127), cqb = w (c 128..255)
        const int cqa = w - 4, cqb = w;
        f32x16 aA0, aA1, aB0, aB1;
#pragma unroll
        for (int r = 0; r < 16; ++r) { aA0[r] = 0.f; aA1[r] = 0.f; aB0[r] = 0.f; aB1[r] = 0.f; }

        short8 vp[8];                              // rolling V buffer
        const size_t vbA = ((size_t)(b * 8 + cqa) * 256 + jh * 128) * 512 + lane * 8;
        const size_t vbB = ((size_t)(b * 8 + cqb) * 256 + jh * 128) * 512 + lane * 8;

        // prologue: vp <- (cqa, step 0)
#pragma unroll
        for (int kc = 0; kc < 8; ++kc)
            vp[kc] = *reinterpret_cast<const short8*>(&vfrag[vbA + kc * 512]);
        __syncthreads();                           // (1)

#pragma unroll 1
        for (int s = 0; s < 16; ++s) {
            const int buf = s & 1;
            // phase A: consume (cqa, s), prefetch (cqb, s)
            {
                const size_t pB = vbB + (size_t)s * 8 * 512;
#pragma unroll
                for (int kc = 0; kc < 8; ++kc) {
                    short8 a = vp[kc];             // break WAR so reload issues early
                    vp[kc] = *reinterpret_cast<const short8*>(&vfrag[pB + kc * 512]);
                    short8 B0 = *reinterpret_cast<const short8*>(&Ps[(buf * 8 + kc) * 512 + lane * 8]);
                    short8 B1 = *reinterpret_cast<const short8*>(&Ps[((2 + buf) * 8 + kc) * 512 + lane * 8]);
                    aA0 = __builtin_amdgcn_mfma_f32_32x32x16_bf16(a, B0, aA0, 0, 0, 0);
                    aA1 = __builtin_amdgcn_mfma_f32_32x32x16_bf16(a, B1, aA1, 0, 0, 0);
                }
            }
            // phase B: consume (cqb, s), prefetch (cqa, s+1)
            // (s=15 prefetch reads the adjacent cqa+1 region: always in-bounds
            //  of vfrag since cqa<=3; data unused.)
            {
                const size_t pA = vbA + (size_t)(s + 1) * 8 * 512;
#pragma unroll
                for (int kc = 0; kc < 8; ++kc) {
                    short8 a = vp[kc];
                    vp[kc] = *reinterpret_cast<const short8*>(&vfrag[pA + kc * 512]);
                    short8 B0 = *reinterpret_cast<const short8*>(&Ps[(buf * 8 + kc) * 512 + lane * 8]);
                    short8 B1 = *reinterpret_cast<const short8*>(&Ps[((2 + buf) * 8 + kc) * 512 + lane * 8]);
                    aB0 = __builtin_amdgcn_mfma_f32_32x32x16_bf16(a, B0, aB0, 0, 0, 0);
                    aB1 = __builtin_amdgcn_mfma_f32_32x32x16_bf16(a, B1, aB1, 0, 0, 0);
                }
            }
            __syncthreads();                       // (2..17)
        }
        __syncthreads();                           // (18) matches E-waves' sred barrier

        // partial O (linear [b][c][i]): jh0 fp32 parked in out, jh1 bf16 in opart
#pragma unroll
        for (int cqi = 0; cqi < 2; ++cqi) {
            const int cq = cqi ? cqb : cqa;
#pragma unroll
            for (int itt = 0; itt < 2; ++itt) {
                const f32x16 A = cqi ? (itt ? aB1 : aB0) : (itt ? aA1 : aA0);
#pragma unroll
                for (int r = 0; r < 16; ++r) {
                    int c = cq * 32 + (r & 3) + 8 * (r >> 2) + 4 * hi;
                    size_t idx = (size_t)(b * CIN + c) * NPIX + ipos * 64 + itt * 32 + li;
                    if (jh == 0) out[idx] = A[r];
                    else         opart[idx] = f2bf(A[r]);
                }
            }
        }
    }
}

// ---------------------------------------------------------------------------
// Merge: out = gamma * (O0 + O1) / (l0 + l1) + x.  Pure streaming, ~59 MB.
// grid 4096, block 256; thread handles 4 consecutive i.
__global__ __launch_bounds__(256) void merge_kernel(
        const unsigned short* __restrict__ opart, const float* __restrict__ lpart,
        const float* __restrict__ xin, const float* __restrict__ gamma,
        float* __restrict__ out) {
    const size_t idx4 = ((size_t)blockIdx.x * 256 + threadIdx.x) * 4;
    const size_t i  = idx4 & (NPIX - 1);
    const size_t b  = idx4 >> 20;                 // idx4 / (CIN*NPIX)
    float4 o0 = *reinterpret_cast<const float4*>(&out[idx4]);
    float4 xv = *reinterpret_cast<const float4*>(&xin[idx4]);
    float4 l0 = *reinterpret_cast<const float4*>(&lpart[b * NPIX + i]);
    float4 l1 = *reinterpret_cast<const float4*>(&lpart[(4 + b) * NPIX + i]);
    const unsigned short* op = &opart[idx4];
    const float g = gamma[0];
    float4 o;
    o.x = g * (o0.x + bf2f(op[0])) / (l0.x + l1.x) + xv.x;
    o.y = g * (o0.y + bf2f(op[1])) / (l0.y + l1.y) + xv.y;
    o.z = g * (o0.z + bf2f(op[2])) / (l0.z + l1.z) + xv.z;
    o.w = g * (o0.w + bf2f(op[3])) / (l0.w + l1.w) + xv.w;
    *reinterpret_cast<float4*>(&out[idx4]) = o;
}

extern "C" void kernel_launch(void* const* d_in, const int* in_sizes, int n_in,
                              void* d_out, int out_size, void* d_ws, size_t ws_size,
                              hipStream_t stream) {
    const float* x     = (const float*)d_in[0];
    const float* wq    = (const float*)d_in[1];
    const float* bq    = (const float*)d_in[2];
    const float* wk    = (const float*)d_in[3];
    const float* bk    = (const float*)d_in[4];
    const float* wv    = (const float*)d_in[5];
    const float* bv    = (const float*)d_in[6];
    const float* gamma = (const float*)d_in[7];
    float* out = (float*)d_out;

    unsigned short* qf    = (unsigned short*)d_ws;       // 1 MB
    unsigned short* kf    = qf + (size_t)524288;         // 1 MB
    unsigned short* vf    = kf + (size_t)524288;         // 8 MB
    unsigned short* wqh   = vf + (size_t)4194304;
    unsigned short* wql   = wqh + 8192;
    unsigned short* wkh   = wql + 8192;
    unsigned short* wkl   = wkh + 8192;
    unsigned short* wvh   = wkl + 8192;                  // 160 KB of weight frags
    unsigned short* opart = wvh + 65536;                 // 8.4 MB (jh1 bf16 partial O)
    float*          lpart = (float*)(opart + 4194304);   // 128 KB
    // total ~18.8 MB of d_ws

    wprep_kernel<<<dim3(16, 12), 64, 0, stream>>>(wq, wk, wv, wqh, wql, wkh, wkl, wvh);
    projall_kernel<<<dim3(128, 4), 512, 0, stream>>>(x, wqh, wql, wkh, wkl, wvh,
                                                     bq, bk, bv, qf, kf, vf);
    attnv_kernel<<<dim3(512), 512, 0, stream>>>(qf, kf, vf, opart, lpart, out);
    merge_kernel<<<dim3(4096), 256, 0, stream>>>(opart, lpart, x, gamma, out);
}

// Round 4
// 148.248 us; speedup vs baseline: 1.0046x; 1.0046x over previous
//
#include <hip/hip_runtime.h>
#include <hip/hip_bf16.h>

#define NPIX 4096
#define CIN  256
#define DK   32

typedef __attribute__((ext_vector_type(8))) short short8;     // 8 bf16 = one MFMA A/B frag reg group
typedef __attribute__((ext_vector_type(16))) float f32x16;    // 32x32 C/D frag

__device__ __forceinline__ unsigned short f2bf(float f) {
    unsigned int u = __float_as_uint(f);
    return (unsigned short)((u + 0x7fffu + ((u >> 16) & 1u)) >> 16);   // RNE
}
__device__ __forceinline__ float bf2f(unsigned short h) {
    return __uint_as_float(((unsigned int)h) << 16);
}
// packed fp32x2 -> bf16x2 via v_cvt_pk_bf16_f32 (RNE), low short = a
__device__ __forceinline__ unsigned int f2bf2(float a, float b) {
    __hip_bfloat162 h = __float22bfloat162_rn(make_float2(a, b));
    unsigned int u;
    __builtin_memcpy(&u, &h, 4);
    return u;
}

// ---------------------------------------------------------------------------
// Weight prep: wq/wk hi+residual B-frags, wv hi B-frags.
// grid (16 kchunks, 12), 64 threads.
__global__ void wprep_kernel(const float* __restrict__ wq, const float* __restrict__ wk,
                             const float* __restrict__ wv,
                             unsigned short* __restrict__ wqh, unsigned short* __restrict__ wql,
                             unsigned short* __restrict__ wkh, unsigned short* __restrict__ wkl,
                             unsigned short* __restrict__ wvh) {
    const int lane = threadIdx.x & 63, li = lane & 31, hi = lane >> 5;
    const int kc = blockIdx.x, y = blockIdx.y;
    if (y < 4) {
        const float* m = (y < 2) ? wq : wk;
        short8 h8, l8;
#pragma unroll
        for (int e = 0; e < 8; ++e) {
            float v = m[li * CIN + kc * 16 + hi * 8 + e];
            unsigned short hb = f2bf(v);
            h8[e] = (short)hb;
            l8[e] = (short)f2bf(v - bf2f(hb));
        }
        unsigned short* dst = (y == 0) ? wqh : (y == 1) ? wql : (y == 2) ? wkh : wkl;
        *reinterpret_cast<short8*>(&dst[kc * 512 + lane * 8]) = (y & 1) ? l8 : h8;
    } else {
        const int cblk = y - 4;
        short8 h8;
#pragma unroll
        for (int e = 0; e < 8; ++e)
            h8[e] = (short)f2bf(wv[(cblk * 32 + li) * CIN + kc * 16 + hi * 8 + e]);
        *reinterpret_cast<short8*>(&wvh[(cblk * 16 + kc) * 512 + lane * 8]) = h8;
    }
}

// ---------------------------------------------------------------------------
// Fused prep + Q/K/V projection (unchanged). grid (128, 4), block 512.
__global__ __launch_bounds__(512) void projall_kernel(
        const float* __restrict__ x,
        const unsigned short* __restrict__ wqh, const unsigned short* __restrict__ wql,
        const unsigned short* __restrict__ wkh, const unsigned short* __restrict__ wkl,
        const unsigned short* __restrict__ wvh,
        const float* __restrict__ bq, const float* __restrict__ bk, const float* __restrict__ bv,
        unsigned short* __restrict__ qfrag, unsigned short* __restrict__ kfrag,
        unsigned short* __restrict__ vfrag) {
    __shared__ float xs[64][36];
    __shared__ unsigned short xhf[16 * 512];
    __shared__ unsigned short xlf[16 * 512];
    __shared__ unsigned short ts[2][32][40];

    const int t = threadIdx.x, lane = t & 63, li = lane & 31, hi = lane >> 5, w = t >> 6;
    const int nblk = blockIdx.x, b = blockIdx.y;
    const int n0 = nblk * 32;

    for (int cb = 0; cb < 4; ++cb) {
        {
            int c = t >> 3, n4 = (t & 7) * 4;
            float4 v = *reinterpret_cast<const float4*>(
                &x[(size_t)(b * CIN + cb * 64 + c) * NPIX + n0 + n4]);
            xs[c][n4 + 0] = v.x; xs[c][n4 + 1] = v.y;
            xs[c][n4 + 2] = v.z; xs[c][n4 + 3] = v.w;
        }
        __syncthreads();
        {
            const int kc = w & 3;
            const bool isL = (w >= 4);
            short8 f;
#pragma unroll
            for (int e = 0; e < 8; ++e) {
                float v = xs[kc * 16 + hi * 8 + e][li];
                unsigned short hb = f2bf(v);
                f[e] = isL ? (short)f2bf(v - bf2f(hb)) : (short)hb;
            }
            unsigned short* dst = isL ? xlf : xhf;
            *reinterpret_cast<short8*>(&dst[(cb * 4 + kc) * 512 + lane * 8]) = f;
        }
        __syncthreads();
    }

    if (w < 2) {
        const unsigned short* wh = (w == 0) ? wqh : wkh;
        const unsigned short* wl = (w == 0) ? wql : wkl;
        const float* bias = (w == 0) ? bq : bk;
        f32x16 acc;
#pragma unroll
        for (int r = 0; r < 16; ++r) acc[r] = 0.f;
        for (int kc = 0; kc < 16; ++kc) {
            short8 ah = *reinterpret_cast<const short8*>(&xhf[kc * 512 + lane * 8]);
            short8 al = *reinterpret_cast<const short8*>(&xlf[kc * 512 + lane * 8]);
            short8 whf = *reinterpret_cast<const short8*>(&wh[kc * 512 + lane * 8]);
            short8 wlf = *reinterpret_cast<const short8*>(&wl[kc * 512 + lane * 8]);
            acc = __builtin_amdgcn_mfma_f32_32x32x16_bf16(ah, whf, acc, 0, 0, 0);
            acc = __builtin_amdgcn_mfma_f32_32x32x16_bf16(al, whf, acc, 0, 0, 0);
            acc = __builtin_amdgcn_mfma_f32_32x32x16_bf16(ah, wlf, acc, 0, 0, 0);
        }
        const float bs = bias[li];
#pragma unroll
        for (int r = 0; r < 16; ++r) {
            int row = (r & 3) + 8 * (r >> 2) + 4 * hi;
            ts[w][row][li] = f2bf(acc[r] + bs);
        }
        unsigned short* dstf = (w == 0) ? qfrag : kfrag;
#pragma unroll
        for (int dh = 0; dh < 2; ++dh) {
            short8 f = *reinterpret_cast<const short8*>(&ts[w][li][dh * 16 + hi * 8]);
            *reinterpret_cast<short8*>(
                &dstf[((size_t)(b * 128 + nblk) * 2 + dh) * 512 + lane * 8]) = f;
        }
    } else {
        const int w2 = w - 2;
        const int njob = (w2 < 2) ? 2 : 1;
        for (int jj = 0; jj < njob; ++jj) {
            const int cblk = w2 + jj * 6;
            f32x16 acc;
#pragma unroll
            for (int r = 0; r < 16; ++r) acc[r] = 0.f;
            for (int kc = 0; kc < 16; ++kc) {
                short8 xb = *reinterpret_cast<const short8*>(&xhf[kc * 512 + lane * 8]);
                short8 wf = *reinterpret_cast<const short8*>(&wvh[(cblk * 16 + kc) * 512 + lane * 8]);
                acc = __builtin_amdgcn_mfma_f32_32x32x16_bf16(xb, wf, acc, 0, 0, 0);
            }
            const float bvv = bv[cblk * 32 + li];
#pragma unroll
            for (int g = 0; g < 2; ++g) {
                short8 sv;
#pragma unroll
                for (int e = 0; e < 8; ++e) sv[e] = (short)f2bf(acc[g * 8 + e] + bvv);
                *reinterpret_cast<short8*>(
                    &vfrag[((size_t)(b * 8 + cblk) * 256 + nblk * 2 + g) * 512 + lane * 8]) = sv;
            }
        }
    }
}

// ---------------------------------------------------------------------------
// Fused attention, j-split, SYMMETRIC waves (round-1 structure, best so far):
// block = 512 threads (8 waves), every wave does one E-unit (it=w>>2, sl=w&3)
// AND one PV-unit (cq=w).
//
// KEY CHANGE this round: Ps is QUAD-buffered (4 slabs per it, 64 KB total)
// and the per-step barrier becomes a per-PAIR barrier (17 -> 9 barriers).
// Rationale: round-1's counters showed only ~30% overlap between the
// matrix/VALU/LDS/L2 phases; with a barrier every step, all 16 waves/CU
// re-align each ~7200 cyc and each wave's independent-work window is a
// single step — too short for the 4 waves/SIMD to slip into complementary
// phases. Doubling the window (2 E-units + 2 PV-units = 36 MFMA + 2 exp
// phases + 2 load phases between syncs) gives the scheduler room to overlap
// pipes across waves. Register-neutral vs round 1 (r3's spill lesson:
// VGPR+AGPR must stay <= 128 at 4 waves/EU).
// sred is aliased onto Ps (only live after the main loop) to stay at the
// 64 KB static-LDS limit; 2 blocks/CU * 64 KB = 128 KB <= 160 KB.
__global__ __launch_bounds__(512, 4) void attnv_kernel(
        const unsigned short* __restrict__ qfrag, const unsigned short* __restrict__ kfrag,
        const unsigned short* __restrict__ vfrag, unsigned short* __restrict__ opart,
        float* __restrict__ lpart, float* __restrict__ out) {
    __shared__ unsigned short Ps[8 * 8 * 512];   // [it*4+buf][jg 8][lane*8], 64 KB

    const int t = threadIdx.x, lane = t & 63, li = lane & 31, hi = lane >> 5, w = t >> 6;
    const int blk = blockIdx.x;
    const int xcd = blk & 7, slot = blk >> 3;
    const int jh = slot & 1, ps = slot >> 1;
    const int b = xcd >> 1;
    const int ipos = (xcd & 1) * 32 + ps;          // 64-i tile in [0,64)
    const int it = w >> 2, sl = w & 3;             // E unit
    const int cq = w;                              // PV unit (32 c)

    // persistent Q frag (E unit's i-tile)
    short8 qb0, qb1;
    {
        size_t qoff = ((size_t)(b * 128 + ipos * 2 + it) * 2) * 512 + lane * 8;
        qb0 = *reinterpret_cast<const short8*>(&qfrag[qoff]);
        qb1 = *reinterpret_cast<const short8*>(&qfrag[qoff + 512]);
    }
    float ssum = 0.f;

    f32x16 acc0, acc1;
#pragma unroll
    for (int r = 0; r < 16; ++r) { acc0[r] = 0.f; acc1[r] = 0.f; }

    short8 kp0, kp1;                               // K prefetch (for next do_E step)
    short8 vp[8];                                  // V frags (rolling: holds step-s data)

    auto kload = [&](int s) {
        size_t koff = ((size_t)(b * 128 + jh * 64 + s * 4 + sl) * 2) * 512 + lane * 8;
        kp0 = *reinterpret_cast<const short8*>(&kfrag[koff]);
        kp1 = *reinterpret_cast<const short8*>(&kfrag[koff + 512]);
    };
    auto vload = [&](int s) {
        size_t vb = ((size_t)(b * 8 + cq) * 256 + jh * 128 + s * 8) * 512 + lane * 8;
#pragma unroll
        for (int kc = 0; kc < 8; ++kc)
            vp[kc] = *reinterpret_cast<const short8*>(&vfrag[vb + kc * 512]);
    };
    auto do_E = [&](int s) {                       // consumes kp0/kp1 (preloaded for s)
        f32x16 e;
#pragma unroll
        for (int r = 0; r < 16; ++r) e[r] = 0.f;
        e = __builtin_amdgcn_mfma_f32_32x32x16_bf16(kp0, qb0, e, 0, 0, 0);
        e = __builtin_amdgcn_mfma_f32_32x32x16_bf16(kp1, qb1, e, 0, 0, 0);
        const int buf = s & 3;                     // quad buffer
#pragma unroll
        for (int g = 0; g < 2; ++g) {
            float p0 = __expf(e[g * 8 + 0]), p1 = __expf(e[g * 8 + 1]);
            float p2 = __expf(e[g * 8 + 2]), p3 = __expf(e[g * 8 + 3]);
            float p4 = __expf(e[g * 8 + 4]), p5 = __expf(e[g * 8 + 5]);
            float p6 = __expf(e[g * 8 + 6]), p7 = __expf(e[g * 8 + 7]);
            ssum += ((p0 + p1) + (p2 + p3)) + ((p4 + p5) + (p6 + p7));
            uint4 pk;
            pk.x = f2bf2(p0, p1); pk.y = f2bf2(p2, p3);
            pk.z = f2bf2(p4, p5); pk.w = f2bf2(p6, p7);
            *reinterpret_cast<uint4*>(
                &Ps[((it * 4 + buf) * 8 + sl * 2 + g) * 512 + lane * 8]) = pk;
        }
    };
    auto do_PV = [&](int s) {                      // consumes vp (step s) + Ps buf s&3
        const int buf = s & 3;
        const int spf = (s + 1) & 15;              // next-step V index (wraps at tail)
        const size_t vbn = ((size_t)(b * 8 + cq) * 256 + jh * 128 + spf * 8) * 512 + lane * 8;
#pragma unroll
        for (int kc = 0; kc < 8; ++kc) {
            short8 a = vp[kc];                     // break WAR so reload issues early
            vp[kc] = *reinterpret_cast<const short8*>(&vfrag[vbn + kc * 512]);
            short8 B0 = *reinterpret_cast<const short8*>(&Ps[((0 + buf) * 8 + kc) * 512 + lane * 8]);
            short8 B1 = *reinterpret_cast<const short8*>(&Ps[((4 + buf) * 8 + kc) * 512 + lane * 8]);
            acc0 = __builtin_amdgcn_mfma_f32_32x32x16_bf16(a, B0, acc0, 0, 0, 0);
            acc1 = __builtin_amdgcn_mfma_f32_32x32x16_bf16(a, B1, acc1, 0, 0, 0);
        }
    };

    // prologue: E(0), E(1) written before first barrier; kp holds step 2.
    kload(0);
    vload(0);
    do_E(0);
    kload(1);
    do_E(1);
    kload(2);
    __syncthreads();                               // (1)

    // pair loop: one barrier per TWO steps. Within a pair:
    //   E(k+2), E(k+3) write slabs (k+2)&3, (k+3)&3;
    //   PV(k), PV(k+1) read slabs k&3, (k+1)&3 — disjoint (quad buffer).
    // Slab (k+2)&3 was last read by PV(k-2), completed before the previous
    // pair barrier.
#pragma unroll 1
    for (int k = 0; k < 16; k += 2) {
        if (k + 2 < 16) {
            do_E(k + 2);                           // consumes kp (k+2)
            kload(k + 3);
            do_E(k + 3);                           // exp/pack of E(k+2) covers this load
            if (k + 4 < 16) kload(k + 4);
        }
        do_PV(k);                                  // rolling vload(k+1)
        do_PV(k + 1);                              // rolling vload(k+2)
        __syncthreads();                           // (2..9)
    }

    // row sums: wave w holds (it, sl) partial over its 32-j slice.
    // sred aliases Ps (dead after the final loop barrier).
    float* sredf = reinterpret_cast<float*>(Ps);   // [2][4][32]
    ssum += __shfl_xor(ssum, 32);
    if (lane < 32) sredf[(it * 4 + sl) * 32 + li] = ssum;
    __syncthreads();                               // (10)
    if (sl == 0 && lane < 32) {
        float lt = sredf[(it * 4 + 0) * 32 + li] + sredf[(it * 4 + 1) * 32 + li]
                 + sredf[(it * 4 + 2) * 32 + li] + sredf[(it * 4 + 3) * 32 + li];
        lpart[((size_t)jh * 4 + b) * NPIX + ipos * 64 + it * 32 + li] = lt;
    }

    // partial O (linear [b][c][i]): jh0 fp32 parked in out, jh1 bf16 in opart
#pragma unroll
    for (int itt = 0; itt < 2; ++itt) {
        const f32x16& A = itt ? acc1 : acc0;
#pragma unroll
        for (int r = 0; r < 16; ++r) {
            int c = cq * 32 + (r & 3) + 8 * (r >> 2) + 4 * hi;
            size_t idx = (size_t)(b * CIN + c) * NPIX + ipos * 64 + itt * 32 + li;
            if (jh == 0) out[idx] = A[r];
            else         opart[idx] = f2bf(A[r]);
        }
    }
}

// ---------------------------------------------------------------------------
// Merge: out = gamma * (O0 + O1) / (l0 + l1) + x.  Pure streaming, ~59 MB.
// grid 4096, block 256; thread handles 4 consecutive i.
__global__ __launch_bounds__(256) void merge_kernel(
        const unsigned short* __restrict__ opart, const float* __restrict__ lpart,
        const float* __restrict__ xin, const float* __restrict__ gamma,
        float* __restrict__ out) {
    const size_t idx4 = ((size_t)blockIdx.x * 256 + threadIdx.x) * 4;
    const size_t i  = idx4 & (NPIX - 1);
    const size_t b  = idx4 >> 20;                 // idx4 / (CIN*NPIX)
    float4 o0 = *reinterpret_cast<const float4*>(&out[idx4]);
    float4 xv = *reinterpret_cast<const float4*>(&xin[idx4]);
    float4 l0 = *reinterpret_cast<const float4*>(&lpart[b * NPIX + i]);
    float4 l1 = *reinterpret_cast<const float4*>(&lpart[(4 + b) * NPIX + i]);
    ushort4 opv = *reinterpret_cast<const ushort4*>(&opart[idx4]);   // one 8B load
    const float g = gamma[0];
    float4 o;
    o.x = g * (o0.x + bf2f(opv.x)) / (l0.x + l1.x) + xv.x;
    o.y = g * (o0.y + bf2f(opv.y)) / (l0.y + l1.y) + xv.y;
    o.z = g * (o0.z + bf2f(opv.z)) / (l0.z + l1.z) + xv.z;
    o.w = g * (o0.w + bf2f(opv.w)) / (l0.w + l1.w) + xv.w;
    *reinterpret_cast<float4*>(&out[idx4]) = o;
}

extern "C" void kernel_launch(void* const* d_in, const int* in_sizes, int n_in,
                              void* d_out, int out_size, void* d_ws, size_t ws_size,
                              hipStream_t stream) {
    const float* x     = (const float*)d_in[0];
    const float* wq    = (const float*)d_in[1];
    const float* bq    = (const float*)d_in[2];
    const float* wk    = (const float*)d_in[3];
    const float* bk    = (const float*)d_in[4];
    const float* wv    = (const float*)d_in[5];
    const float* bv    = (const float*)d_in[6];
    const float* gamma = (const float*)d_in[7];
    float* out = (float*)d_out;

    unsigned short* qf    = (unsigned short*)d_ws;       // 1 MB
    unsigned short* kf    = qf + (size_t)524288;         // 1 MB
    unsigned short* vf    = kf + (size_t)524288;         // 8 MB
    unsigned short* wqh   = vf + (size_t)4194304;
    unsigned short* wql   = wqh + 8192;
    unsigned short* wkh   = wql + 8192;
    unsigned short* wkl   = wkh + 8192;
    unsigned short* wvh   = wkl + 8192;                  // 160 KB of weight frags
    unsigned short* opart = wvh + 65536;                 // 8.4 MB (jh1 bf16 partial O)
    float*          lpart = (float*)(opart + 4194304);   // 128 KB
    // total ~18.8 MB of d_ws

    wprep_kernel<<<dim3(16, 12), 64, 0, stream>>>(wq, wk, wv, wqh, wql, wkh, wkl, wvh);
    projall_kernel<<<dim3(128, 4), 512, 0, stream>>>(x, wqh, wql, wkh, wkl, wvh,
                                                     bq, bk, bv, qf, kf, vf);
    attnv_kernel<<<dim3(512), 512, 0, stream>>>(qf, kf, vf, opart, lpart, out);
    merge_kernel<<<dim3(4096), 256, 0, stream>>>(opart, lpart, x, gamma, out);
}